// Round 1
// baseline (460.881 us; speedup 1.0000x reference)
//
#include <hip/hip_runtime.h>

// Problem constants (match reference file)
constexpr int K    = 8192;
constexpr int N4   = 6144;   // int4 rows
constexpr int N8   = 2048;   // uint8 rows
constexpr int NT   = N4 + N8; // 8192 output columns
constexpr int NG   = K / 128; // 64 groups per int4 row

// ---------------------------------------------------------------------------
// Prep: x2 = x / awq_scales ; fwd = inverse of inv_perm
// ---------------------------------------------------------------------------
__global__ void prep_kernel(const float* __restrict__ x,
                            const float* __restrict__ awq,
                            const int*   __restrict__ inv_perm,
                            float* __restrict__ x2,
                            int*   __restrict__ fwd) {
    int tid = blockIdx.x * blockDim.x + threadIdx.x;
    if (tid < 16 * K) {
        x2[tid] = x[tid] / awq[tid & (K - 1)];
    }
    if (tid < NT) {
        // y_out[:, j] = y_cat[:, inv_perm[j]]  =>  source s lands at column fwd[s]
        fwd[inv_perm[tid]] = tid;
    }
}

// ---------------------------------------------------------------------------
// Main GEMV: one wave (block of 64) handles 4 consecutive source rows.
//   int4 rows  : y = sum_g s4[n,g] * sum_{k in g} x2[m,k]*(w4[n,k]-8)
//   uint8 rows : y = s8[n] * sum_k x2[m,k]*(w8[n,k]-128)   (algebraic merge of
//                hi/lo nibbles + 8*s*sum_x correction from the reference)
// ---------------------------------------------------------------------------
__global__ __launch_bounds__(64, 3)
void qgemv_kernel(const float* __restrict__ x2,
                  const int*   __restrict__ w4,
                  const float* __restrict__ s4,
                  const int*   __restrict__ w8,
                  const float* __restrict__ s8,
                  const float* __restrict__ bias,
                  const int*   __restrict__ fwd,
                  float* __restrict__ out) {
    __shared__ float red[16][65];   // stride 65 -> conflict-free transpose

    const int lane  = threadIdx.x;          // 0..63
    const int nbase = blockIdx.x * 4;       // 4 rows per wave, type-uniform
    const int k0l   = lane * 4;

    float acc[4][16];
    #pragma unroll
    for (int r = 0; r < 4; ++r)
        #pragma unroll
        for (int m = 0; m < 16; ++m) acc[r][m] = 0.f;

    if (nbase < N4) {
        // ---------------- int4 path ----------------
        const int* wr = w4 + (size_t)nbase * K;
        #pragma unroll 1
        for (int it = 0; it < K / 256; ++it) {
            const int k0 = it * 256 + k0l;
            const int g  = it * 2 + (lane >> 5);   // group = k0/128

            // dequantize 4 rows x 4 weights, scale folded in
            float wf[4][4];
            #pragma unroll
            for (int r = 0; r < 4; ++r) {
                const int4 w  = *(const int4*)(wr + (size_t)r * K + k0);
                const float s = s4[(nbase + r) * NG + g];
                wf[r][0] = ((float)w.x - 8.f) * s;
                wf[r][1] = ((float)w.y - 8.f) * s;
                wf[r][2] = ((float)w.z - 8.f) * s;
                wf[r][3] = ((float)w.w - 8.f) * s;
            }
            #pragma unroll
            for (int m = 0; m < 16; ++m) {
                const float4 xv = *(const float4*)(x2 + m * K + k0);
                #pragma unroll
                for (int r = 0; r < 4; ++r) {
                    acc[r][m] += xv.x * wf[r][0] + xv.y * wf[r][1]
                               + xv.z * wf[r][2] + xv.w * wf[r][3];
                }
            }
        }
    } else {
        // ---------------- uint8 path ----------------
        const int* wr = w8 + (size_t)(nbase - N4) * K;
        #pragma unroll 1
        for (int it = 0; it < K / 256; ++it) {
            const int k0 = it * 256 + k0l;

            float wf[4][4];
            #pragma unroll
            for (int r = 0; r < 4; ++r) {
                const int4 w = *(const int4*)(wr + (size_t)r * K + k0);
                wf[r][0] = (float)w.x - 128.f;
                wf[r][1] = (float)w.y - 128.f;
                wf[r][2] = (float)w.z - 128.f;
                wf[r][3] = (float)w.w - 128.f;
            }
            #pragma unroll
            for (int m = 0; m < 16; ++m) {
                const float4 xv = *(const float4*)(x2 + m * K + k0);
                #pragma unroll
                for (int r = 0; r < 4; ++r) {
                    acc[r][m] += xv.x * wf[r][0] + xv.y * wf[r][1]
                               + xv.z * wf[r][2] + xv.w * wf[r][3];
                }
            }
        }
    }

    // ---------------- cross-lane reduction + permuted writeout ----------------
    #pragma unroll 1
    for (int r = 0; r < 4; ++r) {
        __syncthreads();   // protect previous round's reads
        #pragma unroll
        for (int m = 0; m < 16; ++m) red[m][lane] = acc[r][m];
        __syncthreads();

        const int m = lane & 15;
        const int q = lane >> 4;
        float p = 0.f;
        #pragma unroll
        for (int j = 0; j < 16; ++j) p += red[m][q * 16 + j];
        p += __shfl_xor(p, 16, 64);
        p += __shfl_xor(p, 32, 64);

        if (lane < 16) {
            const int n = nbase + r;
            float v = p;
            if (n >= N4) v *= s8[n - N4];
            const int d = fwd[n];
            out[lane * NT + d] = v + bias[d];
        }
    }
}

// ---------------------------------------------------------------------------
extern "C" void kernel_launch(void* const* d_in, const int* in_sizes, int n_in,
                              void* d_out, int out_size, void* d_ws, size_t ws_size,
                              hipStream_t stream) {
    const float* x        = (const float*)d_in[0];
    const int*   w_int4   = (const int*)  d_in[1];
    const float* s_int4   = (const float*)d_in[2];
    const int*   w_uint8  = (const int*)  d_in[3];
    const float* s_int8   = (const float*)d_in[4];
    const float* awq      = (const float*)d_in[5];
    const float* bias     = (const float*)d_in[6];
    const int*   inv_perm = (const int*)  d_in[7];
    // d_in[8] = group_size (==128), compile-time constant here

    float* x2  = (float*)d_ws;                                   // 16*8192 f32 = 512 KB
    int*   fwd = (int*)((char*)d_ws + (size_t)16 * K * sizeof(float)); // 8192 ints

    prep_kernel<<<(16 * K + 255) / 256, 256, 0, stream>>>(x, awq, inv_perm, x2, fwd);
    qgemv_kernel<<<NT / 4, 64, 0, stream>>>(x2, w_int4, s_int4, w_uint8, s_int8,
                                            bias, fwd, (float*)d_out);
}

// Round 2
// 430.876 us; speedup vs baseline: 1.0696x; 1.0696x over previous
//
#include <hip/hip_runtime.h>

// Problem constants (match reference file)
constexpr int K    = 8192;
constexpr int N4   = 6144;   // int4 rows
constexpr int N8   = 2048;   // uint8 rows
constexpr int NT   = N4 + N8; // 8192 output columns
constexpr int NG   = K / 128; // 64 groups per int4 row

// ---------------------------------------------------------------------------
// Prep: x2 = x / awq_scales ; fwd = inverse of inv_perm
// ---------------------------------------------------------------------------
__global__ void prep_kernel(const float* __restrict__ x,
                            const float* __restrict__ awq,
                            const int*   __restrict__ inv_perm,
                            float* __restrict__ x2,
                            int*   __restrict__ fwd) {
    int tid = blockIdx.x * blockDim.x + threadIdx.x;
    if (tid < 16 * K) {
        x2[tid] = x[tid] / awq[tid & (K - 1)];
    }
    if (tid < NT) {
        // y_out[:, j] = y_cat[:, inv_perm[j]]  =>  source s lands at column fwd[s]
        fwd[inv_perm[tid]] = tid;
    }
}

// ---------------------------------------------------------------------------
// Main GEMV: one wave (block of 64) handles 4 consecutive source rows.
//   int4 rows  : y = sum_g s4[n,g] * sum_{k in g} x2[m,k]*(w4[n,k]-8)
//   uint8 rows : y = s8[n] * sum_k x2[m,k]*(w8[n,k]-128)   (algebraic merge of
//                hi/lo nibbles + 8*s*sum_x correction from the reference)
// ---------------------------------------------------------------------------
__global__ __launch_bounds__(64)
void qgemv_kernel(const float* __restrict__ x2,
                  const int*   __restrict__ w4,
                  const float* __restrict__ s4,
                  const int*   __restrict__ w8,
                  const float* __restrict__ s8,
                  const float* __restrict__ bias,
                  const int*   __restrict__ fwd,
                  float* __restrict__ out) {
    __shared__ float red[16][65];   // stride 65 -> conflict-free transpose

    const int lane  = threadIdx.x;          // 0..63
    const int nbase = blockIdx.x * 4;       // 4 rows per wave, type-uniform
    const int k0l   = lane * 4;

    float acc[4][16];
    #pragma unroll
    for (int r = 0; r < 4; ++r)
        #pragma unroll
        for (int m = 0; m < 16; ++m) acc[r][m] = 0.f;

    if (nbase < N4) {
        // ---------------- int4 path ----------------
        const int* wr = w4 + (size_t)nbase * K;
        #pragma unroll 1
        for (int it = 0; it < K / 256; ++it) {
            const int k0 = it * 256 + k0l;
            const int g  = it * 2 + (lane >> 5);   // group = k0/128

            // dequantize 4 rows x 4 weights, scale folded in
            float wf[4][4];
            #pragma unroll
            for (int r = 0; r < 4; ++r) {
                const int4 w  = *(const int4*)(wr + (size_t)r * K + k0);
                const float s = s4[(nbase + r) * NG + g];
                const float m8s = -8.f * s;
                wf[r][0] = (float)w.x * s + m8s;
                wf[r][1] = (float)w.y * s + m8s;
                wf[r][2] = (float)w.z * s + m8s;
                wf[r][3] = (float)w.w * s + m8s;
            }
            #pragma unroll
            for (int m = 0; m < 16; ++m) {
                const float4 xv = *(const float4*)(x2 + m * K + k0);
                #pragma unroll
                for (int r = 0; r < 4; ++r) {
                    acc[r][m] += xv.x * wf[r][0] + xv.y * wf[r][1]
                               + xv.z * wf[r][2] + xv.w * wf[r][3];
                }
            }
        }
    } else {
        // ---------------- uint8 path ----------------
        const int* wr = w8 + (size_t)(nbase - N4) * K;
        #pragma unroll 1
        for (int it = 0; it < K / 256; ++it) {
            const int k0 = it * 256 + k0l;

            float wf[4][4];
            #pragma unroll
            for (int r = 0; r < 4; ++r) {
                const int4 w = *(const int4*)(wr + (size_t)r * K + k0);
                wf[r][0] = (float)w.x - 128.f;
                wf[r][1] = (float)w.y - 128.f;
                wf[r][2] = (float)w.z - 128.f;
                wf[r][3] = (float)w.w - 128.f;
            }
            #pragma unroll
            for (int m = 0; m < 16; ++m) {
                const float4 xv = *(const float4*)(x2 + m * K + k0);
                #pragma unroll
                for (int r = 0; r < 4; ++r) {
                    acc[r][m] += xv.x * wf[r][0] + xv.y * wf[r][1]
                               + xv.z * wf[r][2] + xv.w * wf[r][3];
                }
            }
        }
    }

    // ---------------- cross-lane reduction + permuted writeout ----------------
    // FULLY UNROLLED in r: dynamic r previously demoted acc[][] to scratch
    // (VGPR_Count=60, WRITE_SIZE=66MB). Constant indices keep acc in VGPRs.
    #pragma unroll
    for (int r = 0; r < 4; ++r) {
        __syncthreads();   // protect previous round's reads
        #pragma unroll
        for (int m = 0; m < 16; ++m) red[m][lane] = acc[r][m];
        __syncthreads();

        const int m = lane & 15;
        const int q = lane >> 4;
        float p = 0.f;
        #pragma unroll
        for (int j = 0; j < 16; ++j) p += red[m][q * 16 + j];
        p += __shfl_xor(p, 16, 64);
        p += __shfl_xor(p, 32, 64);

        if (lane < 16) {
            const int n = nbase + r;
            float v = p;
            if (n >= N4) v *= s8[n - N4];
            const int d = fwd[n];
            out[lane * NT + d] = v + bias[d];
        }
    }
}

// ---------------------------------------------------------------------------
extern "C" void kernel_launch(void* const* d_in, const int* in_sizes, int n_in,
                              void* d_out, int out_size, void* d_ws, size_t ws_size,
                              hipStream_t stream) {
    const float* x        = (const float*)d_in[0];
    const int*   w_int4   = (const int*)  d_in[1];
    const float* s_int4   = (const float*)d_in[2];
    const int*   w_uint8  = (const int*)  d_in[3];
    const float* s_int8   = (const float*)d_in[4];
    const float* awq      = (const float*)d_in[5];
    const float* bias     = (const float*)d_in[6];
    const int*   inv_perm = (const int*)  d_in[7];
    // d_in[8] = group_size (==128), compile-time constant here

    float* x2  = (float*)d_ws;                                   // 16*8192 f32 = 512 KB
    int*   fwd = (int*)((char*)d_ws + (size_t)16 * K * sizeof(float)); // 8192 ints

    prep_kernel<<<(16 * K + 255) / 256, 256, 0, stream>>>(x, awq, inv_perm, x2, fwd);
    qgemv_kernel<<<NT / 4, 64, 0, stream>>>(x2, w_int4, s_int4, w_uint8, s_int8,
                                            bias, fwd, (float*)d_out);
}

// Round 3
// 339.491 us; speedup vs baseline: 1.3576x; 1.2692x over previous
//
#include <hip/hip_runtime.h>

// Problem constants (match reference file)
constexpr int K    = 8192;
constexpr int N4   = 6144;    // int4 rows
constexpr int N8   = 2048;    // uint8 rows
constexpr int NT   = N4 + N8; // 8192 output columns (== K, convenient)
constexpr int NG   = K / 128; // 64 groups per int4 row
constexpr int SPLIT = 4;      // split-K factor
constexpr int KS    = K / SPLIT;   // 2048 k per split
constexpr int ITERS = KS / 256;    // 8 iterations of 256 k

// ---------------------------------------------------------------------------
// Prep: x2 = x / awq_scales ; fwd = inverse of inv_perm ; out = bias (atomics
// from qgemv accumulate on top).  16*K == 16*NT == 131072 threads.
// ---------------------------------------------------------------------------
__global__ void prep_kernel(const float* __restrict__ x,
                            const float* __restrict__ awq,
                            const int*   __restrict__ inv_perm,
                            const float* __restrict__ bias,
                            float* __restrict__ x2,
                            int*   __restrict__ fwd,
                            float* __restrict__ out) {
    const int tid = blockIdx.x * blockDim.x + threadIdx.x;  // 0..131071
    x2[tid]  = x[tid] / awq[tid & (K - 1)];
    out[tid] = bias[tid & (NT - 1)];      // column j = tid % NT
    if (tid < NT) fwd[inv_perm[tid]] = tid;
}

// ---------------------------------------------------------------------------
// Main GEMV. Block = 256 threads (4 waves) = 16 consecutive source rows
// (wave w -> rows nblk*16 + 4w .. +3), k-range = split*2048 .. +2047.
// Per iteration the block stages x2[0:16][k0:k0+256] (16 KB) into LDS; each
// wave then streams its 4 weight rows and accumulates 16 m-values per row.
// Partials are atomically added into out (pre-initialized with bias).
//   int4 rows  : y += sum_k x2[m,k]*(w4[n,k]*s - 8s)     (group scale s)
//   uint8 rows : y += s8[n] * sum_k x2[m,k]*(w8[n,k]-128) (nibble merge)
// ---------------------------------------------------------------------------
__global__ __launch_bounds__(256)
void qgemv_kernel(const float* __restrict__ x2,
                  const int*   __restrict__ w4,
                  const float* __restrict__ s4,
                  const int*   __restrict__ w8,
                  const float* __restrict__ s8,
                  const int*   __restrict__ fwd,
                  float* __restrict__ out) {
    // Reused LDS: main loop uses floats [0..4095] as x-tile [16][256];
    // epilogue uses per-wave red areas [w*1040 .. +1039] ([16][65], 65 ≡ 1
    // mod 32 -> conflict-free transpose).
    __shared__ float lds[4 * 1040];
    float* tile = lds;

    const int t    = threadIdx.x;
    const int lane = t & 63;
    const int w    = t >> 6;                    // wave 0..3
    const int nblk = blockIdx.x & 511;          // n-group (16 rows)
    const int spl  = blockIdx.x >> 9;           // split 0..3
    const int nb   = nblk * 16 + w * 4;         // this wave's first row
    const int kb   = spl * KS;                  // k base

    float acc[4][16];
    #pragma unroll
    for (int r = 0; r < 4; ++r)
        #pragma unroll
        for (int m = 0; m < 16; ++m) acc[r][m] = 0.f;

    const bool is4 = (nb < N4);
    const int* wr  = is4 ? (w4 + (size_t)nb * K) : (w8 + (size_t)(nb - N4) * K);

    #pragma unroll 1
    for (int it = 0; it < ITERS; ++it) {
        const int k0 = kb + it * 256;

        // ---- stage x-tile: wave w loads rows {w, 4+w, 8+w, 12+w} ----
        #pragma unroll
        for (int q = 0; q < 4; ++q) {
            const int m = q * 4 + w;
            const float4 v = *(const float4*)(x2 + (size_t)m * K + k0 + lane * 4);
            *(float4*)(tile + m * 256 + lane * 4) = v;
        }
        __syncthreads();

        // ---- weights: 4 rows x 4 k-elems per lane, batched loads ----
        const int kl = k0 + lane * 4;
        float wf[4][4];
        if (is4) {
            const int g = spl * (KS / 128) + it * 2 + (lane >> 5);
            #pragma unroll
            for (int r = 0; r < 4; ++r) {
                const int4 wv = *(const int4*)(wr + (size_t)r * K + kl);
                const float s   = s4[(nb + r) * NG + g];
                const float m8s = -8.f * s;
                wf[r][0] = (float)wv.x * s + m8s;
                wf[r][1] = (float)wv.y * s + m8s;
                wf[r][2] = (float)wv.z * s + m8s;
                wf[r][3] = (float)wv.w * s + m8s;
            }
        } else {
            #pragma unroll
            for (int r = 0; r < 4; ++r) {
                const int4 wv = *(const int4*)(wr + (size_t)r * K + kl);
                wf[r][0] = (float)wv.x - 128.f;
                wf[r][1] = (float)wv.y - 128.f;
                wf[r][2] = (float)wv.z - 128.f;
                wf[r][3] = (float)wv.w - 128.f;
            }
        }

        // ---- FMA: 16 m-rows from LDS ----
        #pragma unroll
        for (int m = 0; m < 16; ++m) {
            const float4 xv = *(const float4*)(tile + m * 256 + lane * 4);
            #pragma unroll
            for (int r = 0; r < 4; ++r) {
                acc[r][m] += xv.x * wf[r][0] + xv.y * wf[r][1]
                           + xv.z * wf[r][2] + xv.w * wf[r][3];
            }
        }
        __syncthreads();   // tile consumed; safe to restage
    }

    // ---- cross-lane reduction + atomic writeout (per-wave red area) ----
    float* red = lds + w * 1040;   // [16][65]
    #pragma unroll
    for (int r = 0; r < 4; ++r) {
        __syncthreads();           // uniform across block; orders red reuse
        #pragma unroll
        for (int m = 0; m < 16; ++m) red[m * 65 + lane] = acc[r][m];
        __syncthreads();

        const int m = lane & 15;
        const int q = lane >> 4;
        float p = 0.f;
        #pragma unroll
        for (int j = 0; j < 16; ++j) p += red[m * 65 + q * 16 + j];
        p += __shfl_xor(p, 16, 64);
        p += __shfl_xor(p, 32, 64);

        if (lane < 16) {
            const int n = nb + r;
            float v = p;
            if (n >= N4) v *= s8[n - N4];
            unsafeAtomicAdd(&out[(size_t)lane * NT + fwd[n]], v);
        }
    }
}

// ---------------------------------------------------------------------------
extern "C" void kernel_launch(void* const* d_in, const int* in_sizes, int n_in,
                              void* d_out, int out_size, void* d_ws, size_t ws_size,
                              hipStream_t stream) {
    const float* x        = (const float*)d_in[0];
    const int*   w_int4   = (const int*)  d_in[1];
    const float* s_int4   = (const float*)d_in[2];
    const int*   w_uint8  = (const int*)  d_in[3];
    const float* s_int8   = (const float*)d_in[4];
    const float* awq      = (const float*)d_in[5];
    const float* bias     = (const float*)d_in[6];
    const int*   inv_perm = (const int*)  d_in[7];
    // d_in[8] = group_size (==128), compile-time constant here

    float* x2  = (float*)d_ws;                                        // 512 KB
    int*   fwd = (int*)((char*)d_ws + (size_t)16 * K * sizeof(float)); // 32 KB

    prep_kernel<<<(16 * K) / 256, 256, 0, stream>>>(x, awq, inv_perm, bias,
                                                    x2, fwd, (float*)d_out);
    qgemv_kernel<<<512 * SPLIT, 256, 0, stream>>>(x2, w_int4, s_int4,
                                                  w_uint8, s_int8, fwd,
                                                  (float*)d_out);
}